// Round 1
// baseline (267.090 us; speedup 1.0000x reference)
//
#include <hip/hip_runtime.h>
#include <hip/hip_bf16.h>
#include <math.h>

// Problem constants (fixed by the reference)
#define NB 8
#define NC 9              // channels (== NUM_CLASSES)
#define NK 9              // classes; class 0 excluded from loss
#define PIXELS (768*768)  // 589824 pixels per batch image
#define CHUNK 16384       // pixels handled per block (589824 / 16384 = 36)
#define CHUNKS_PER_PLANE (PIXELS / CHUNK)  // 36
#define BLOCK 256
#define PIX_PER_THREAD (CHUNK / BLOCK)     // 64 pixels -> 16 float4 per thread

// ws layout: sums[NB][8][9] floats (576), then counts[NB][8] floats (64)
#define SUMS_ELEMS (NB * 8 * NC)
#define WS_FLOATS (SUMS_ELEMS + NB * 8)

__global__ __launch_bounds__(BLOCK)
void accum_kernel(const int* __restrict__ masks,
                  const float* __restrict__ outputs,
                  float* __restrict__ sums,    // [NB][8][NC]
                  float* __restrict__ counts)  // [NB][8]
{
    // Grid ordering: idx = (b*CHUNKS_PER_PLANE + chunk)*NC + c
    // -> the 9 channel-blocks for one mask chunk are consecutive (L2 reuse of masks)
    int idx = blockIdx.x;
    int c = idx % NC;
    int gchunk = idx / NC;
    int chunk = gchunk % CHUNKS_PER_PLANE;
    int b = gchunk / CHUNKS_PER_PLANE;

    const float4* __restrict__ out4 =
        (const float4*)(outputs + ((size_t)(b * NC + c)) * PIXELS + (size_t)chunk * CHUNK);
    const int4* __restrict__ m4 =
        (const int4*)(masks + (size_t)b * PIXELS + (size_t)chunk * CHUNK);

    const bool do_count = (c == 0);   // wave-uniform branch

    float s[8];
    float cnt[8];
    #pragma unroll
    for (int k = 0; k < 8; ++k) { s[k] = 0.f; cnt[k] = 0.f; }

    int t = threadIdx.x;

    #pragma unroll 4
    for (int i = 0; i < PIX_PER_THREAD / 4; ++i) {
        float4 v = out4[t + i * BLOCK];
        int4   m = m4[t + i * BLOCK];
        #pragma unroll
        for (int k = 1; k <= 8; ++k) {
            float acc = s[k - 1];
            acc += (m.x == k) ? v.x : 0.f;
            acc += (m.y == k) ? v.y : 0.f;
            acc += (m.z == k) ? v.z : 0.f;
            acc += (m.w == k) ? v.w : 0.f;
            s[k - 1] = acc;
        }
        if (do_count) {
            #pragma unroll
            for (int k = 1; k <= 8; ++k) {
                float acc = cnt[k - 1];
                acc += (m.x == k) ? 1.f : 0.f;
                acc += (m.y == k) ? 1.f : 0.f;
                acc += (m.z == k) ? 1.f : 0.f;
                acc += (m.w == k) ? 1.f : 0.f;
                cnt[k - 1] = acc;
            }
        }
    }

    // wave (64-lane) shuffle reduce each accumulator
    #pragma unroll
    for (int k = 0; k < 8; ++k) {
        float v = s[k];
        #pragma unroll
        for (int off = 32; off > 0; off >>= 1) v += __shfl_down(v, off, 64);
        s[k] = v;
        if (do_count) {
            float w = cnt[k];
            #pragma unroll
            for (int off = 32; off > 0; off >>= 1) w += __shfl_down(w, off, 64);
            cnt[k] = w;
        }
    }

    __shared__ float red_s[BLOCK / 64][8];
    __shared__ float red_c[BLOCK / 64][8];
    int wave = threadIdx.x >> 6;
    int lane = threadIdx.x & 63;
    if (lane == 0) {
        #pragma unroll
        for (int k = 0; k < 8; ++k) { red_s[wave][k] = s[k]; red_c[wave][k] = cnt[k]; }
    }
    __syncthreads();

    if (threadIdx.x < 8) {
        float tot = 0.f, totc = 0.f;
        #pragma unroll
        for (int w = 0; w < BLOCK / 64; ++w) { tot += red_s[w][threadIdx.x]; totc += red_c[w][threadIdx.x]; }
        atomicAdd(&sums[(b * 8 + threadIdx.x) * NC + c], tot);
        if (do_count) atomicAdd(&counts[b * 8 + threadIdx.x], totc);
    }
}

__global__ __launch_bounds__(64)
void finalize_kernel(const float* __restrict__ sums,
                     const float* __restrict__ counts,
                     float* __restrict__ out)
{
    int t = threadIdx.x;        // 0..63
    int b = t >> 3;             // batch
    int cls = t & 7;            // 0..7 -> class cls+1

    float cntv = counts[b * 8 + cls];
    float denom = fmaxf(cntv, 1.0f);

    float p[NC];
    float mx = -INFINITY;
    #pragma unroll
    for (int c = 0; c < NC; ++c) {
        p[c] = sums[(b * 8 + cls) * NC + c] / denom;
        mx = fmaxf(mx, p[c]);
    }
    float se = 0.f;
    #pragma unroll
    for (int c = 0; c < NC; ++c) se += expf(p[c] - mx);
    float lse = logf(se);

    float per = 0.f;
    #pragma unroll
    for (int c = 0; c < NC; ++c) {
        float tgt = (c == cls + 1) ? 0.9f : 0.0125f;
        per -= tgt * (p[c] - mx - lse);
    }

    bool present = cntv > 0.f;
    float val = present ? per : 0.f;
    float np  = present ? 1.f : 0.f;
    #pragma unroll
    for (int off = 32; off > 0; off >>= 1) {
        val += __shfl_down(val, off, 64);
        np  += __shfl_down(np,  off, 64);
    }
    if (t == 0) out[0] = val / fmaxf(np, 1.f);
}

extern "C" void kernel_launch(void* const* d_in, const int* in_sizes, int n_in,
                              void* d_out, int out_size, void* d_ws, size_t ws_size,
                              hipStream_t stream) {
    const int*   masks   = (const int*)d_in[0];
    const float* outputs = (const float*)d_in[1];
    float* sums   = (float*)d_ws;
    float* counts = sums + SUMS_ELEMS;

    // d_ws is poisoned with 0xAA before every call — zero the accumulators.
    hipMemsetAsync(d_ws, 0, WS_FLOATS * sizeof(float), stream);

    int grid = NB * CHUNKS_PER_PLANE * NC;  // 2592 blocks
    accum_kernel<<<grid, BLOCK, 0, stream>>>(masks, outputs, sums, counts);
    finalize_kernel<<<1, 64, 0, stream>>>(sums, counts, (float*)d_out);
}

// Round 2
// 259.004 us; speedup vs baseline: 1.0312x; 1.0312x over previous
//
#include <hip/hip_runtime.h>
#include <hip/hip_bf16.h>
#include <math.h>

// Problem constants (fixed by the reference)
#define NB 8
#define NC 9               // channels (== NUM_CLASSES)
#define PIXELS (768*768)   // 589824 pixels per batch image
#define BLOCK 256
#define PPT 24                         // pixels per thread (6 x int4)
#define CHUNK_PX (BLOCK * PPT)         // 6144
#define NCHUNK (PIXELS / CHUNK_PX)     // 96 exactly
#define NITER (PPT / 4)                // 6 vector iterations

// ws layout: sums[NB][8][NC] floats (576), then counts[NB][8] floats (64)
#define SUMS_ELEMS (NB * 8 * NC)
#define WS_FLOATS (SUMS_ELEMS + NB * 8)

__global__ __launch_bounds__(BLOCK)
void accum_kernel(const int* __restrict__ masks,
                  const float* __restrict__ outputs,
                  float* __restrict__ sums,    // [NB][8][NC]
                  float* __restrict__ counts)  // [NB][8]
{
    int blk = blockIdx.x;
    int chunk = blk % NCHUNK;
    int b = blk / NCHUNK;
    int t = threadIdx.x;
    int wave = t >> 6;
    int lane = t & 63;

    // ---- load mask chunk ONCE into registers (reused for all 9 channels) ----
    const int4* __restrict__ m4 =
        (const int4*)(masks + (size_t)b * PIXELS + (size_t)chunk * CHUNK_PX);
    int4 m[NITER];
    #pragma unroll
    for (int i = 0; i < NITER; ++i) m[i] = m4[t + i * BLOCK];

    __shared__ float red[NC][BLOCK / 64][8];   // per-channel per-wave class sums
    __shared__ float red_c[BLOCK / 64][8];     // per-wave class counts

    // ---- counts (from mask regs only) ----
    {
        float cnt[8];
        #pragma unroll
        for (int k = 0; k < 8; ++k) cnt[k] = 0.f;
        #pragma unroll
        for (int i = 0; i < NITER; ++i) {
            #pragma unroll
            for (int k = 1; k <= 8; ++k) {
                float a = cnt[k - 1];
                a += (m[i].x == k) ? 1.f : 0.f;
                a += (m[i].y == k) ? 1.f : 0.f;
                a += (m[i].z == k) ? 1.f : 0.f;
                a += (m[i].w == k) ? 1.f : 0.f;
                cnt[k - 1] = a;
            }
        }
        #pragma unroll
        for (int k = 0; k < 8; ++k) {
            float v = cnt[k];
            #pragma unroll
            for (int off = 32; off > 0; off >>= 1) v += __shfl_down(v, off, 64);
            if (lane == 0) red_c[wave][k] = v;
        }
    }

    // ---- per-channel accumulation; mask stays in registers ----
    for (int c = 0; c < NC; ++c) {
        const float4* __restrict__ o4 =
            (const float4*)(outputs + ((size_t)(b * NC + c)) * PIXELS
                            + (size_t)chunk * CHUNK_PX);
        float s[8];
        #pragma unroll
        for (int k = 0; k < 8; ++k) s[k] = 0.f;

        #pragma unroll
        for (int i = 0; i < NITER; ++i) {
            float4 v = o4[t + i * BLOCK];
            #pragma unroll
            for (int k = 1; k <= 8; ++k) {
                float a = s[k - 1];
                a += (m[i].x == k) ? v.x : 0.f;
                a += (m[i].y == k) ? v.y : 0.f;
                a += (m[i].z == k) ? v.z : 0.f;
                a += (m[i].w == k) ? v.w : 0.f;
                s[k - 1] = a;
            }
        }

        #pragma unroll
        for (int k = 0; k < 8; ++k) {
            float v = s[k];
            #pragma unroll
            for (int off = 32; off > 0; off >>= 1) v += __shfl_down(v, off, 64);
            if (lane == 0) red[c][wave][k] = v;
        }
    }

    __syncthreads();

    // ---- one atomic per (channel, class) pair; counts from 8 more threads ----
    if (t < NC * 8) {                 // t in [0,72): c = t>>3, k = t&7
        int c = t >> 3;
        int k = t & 7;
        float tot = 0.f;
        #pragma unroll
        for (int w = 0; w < BLOCK / 64; ++w) tot += red[c][w][k];
        atomicAdd(&sums[(b * 8 + k) * NC + c], tot);
    } else if (t < NC * 8 + 8) {      // t in [72,80): class counts
        int k = t - NC * 8;
        float tot = 0.f;
        #pragma unroll
        for (int w = 0; w < BLOCK / 64; ++w) tot += red_c[w][k];
        atomicAdd(&counts[b * 8 + k], tot);
    }
}

__global__ __launch_bounds__(64)
void finalize_kernel(const float* __restrict__ sums,
                     const float* __restrict__ counts,
                     float* __restrict__ out)
{
    int t = threadIdx.x;        // 0..63
    int b = t >> 3;             // batch
    int cls = t & 7;            // 0..7 -> class cls+1

    float cntv = counts[b * 8 + cls];
    float denom = fmaxf(cntv, 1.0f);

    float p[NC];
    float mx = -INFINITY;
    #pragma unroll
    for (int c = 0; c < NC; ++c) {
        p[c] = sums[(b * 8 + cls) * NC + c] / denom;
        mx = fmaxf(mx, p[c]);
    }
    float se = 0.f;
    #pragma unroll
    for (int c = 0; c < NC; ++c) se += expf(p[c] - mx);
    float lse = logf(se);

    float per = 0.f;
    #pragma unroll
    for (int c = 0; c < NC; ++c) {
        float tgt = (c == cls + 1) ? 0.9f : 0.0125f;
        per -= tgt * (p[c] - mx - lse);
    }

    bool present = cntv > 0.f;
    float val = present ? per : 0.f;
    float np  = present ? 1.f : 0.f;
    #pragma unroll
    for (int off = 32; off > 0; off >>= 1) {
        val += __shfl_down(val, off, 64);
        np  += __shfl_down(np,  off, 64);
    }
    if (t == 0) out[0] = val / fmaxf(np, 1.f);
}

extern "C" void kernel_launch(void* const* d_in, const int* in_sizes, int n_in,
                              void* d_out, int out_size, void* d_ws, size_t ws_size,
                              hipStream_t stream) {
    const int*   masks   = (const int*)d_in[0];
    const float* outputs = (const float*)d_in[1];
    float* sums   = (float*)d_ws;
    float* counts = sums + SUMS_ELEMS;

    // d_ws is poisoned with 0xAA before every call — zero the accumulators.
    hipMemsetAsync(d_ws, 0, WS_FLOATS * sizeof(float), stream);

    int grid = NB * NCHUNK;   // 768 blocks = exactly 3 per CU
    accum_kernel<<<grid, BLOCK, 0, stream>>>(masks, outputs, sums, counts);
    finalize_kernel<<<1, 64, 0, stream>>>(sums, counts, (float*)d_out);
}